// Round 4
// baseline (633.347 us; speedup 1.0000x reference)
//
#include <hip/hip_runtime.h>
#include <hip/hip_bf16.h>
#include <stdint.h>

#define S_DIM 2048
#define D_DIM 128
#define QBLK 256
#define KVBLK 32
#define NW 8
#define NXQ (S_DIM / QBLK)   // 8

typedef __attribute__((ext_vector_type(8))) __bf16 bf16x8;
typedef __attribute__((ext_vector_type(4))) float f32x4;
typedef __attribute__((ext_vector_type(2))) unsigned int u32x2;
typedef __attribute__((ext_vector_type(4))) unsigned int u32x4;

__device__ __forceinline__ uint32_t lds_off(const void* p) {
    return (uint32_t)(uintptr_t)p;   // low 32 bits of LDS flat addr = byte offset
}

__device__ __forceinline__ bf16x8 load_cvt8_scaled(const float* __restrict__ p, float s) {
    float4 a = *reinterpret_cast<const float4*>(p);
    float4 b = *reinterpret_cast<const float4*>(p + 4);
    bf16x8 r;
    r[0] = (__bf16)(a.x * s); r[1] = (__bf16)(a.y * s);
    r[2] = (__bf16)(a.z * s); r[3] = (__bf16)(a.w * s);
    r[4] = (__bf16)(b.x * s); r[5] = (__bf16)(b.y * s);
    r[6] = (__bf16)(b.z * s); r[7] = (__bf16)(b.w * s);
    return r;
}

struct StageRegs { float4 k0, k1, v0, v1; };

__global__ __launch_bounds__(512, 2)
void attn_fwd(const float* __restrict__ Q, const float* __restrict__ K,
              const float* __restrict__ V, float* __restrict__ O) {
    // K tile: row-major [KVBLK][128] bf16, byte ^= ((row&7)<<4) swizzle
    // V tile: tr_b16 layout L(kv,d) = 512*(d>>4) + 256*((kv>>2)&1) + 64*(kv>>3) + 16*(kv&3) + (d&15)
    __shared__ __bf16 k_lds[2][KVBLK * D_DIM];
    __shared__ __bf16 v_lds[2][KVBLK * D_DIM];
    __shared__ __bf16 p_lds[NW][2][16][40];

    const int tid  = threadIdx.x;
    const int lane = tid & 63;
    const int wv   = tid >> 6;
    const int g    = lane >> 4;   // 0..3
    const int c    = lane & 15;   // 0..15

    // ---- XCD-pinned block mapping: xcd = bid%8 == bh%8 ----
    const int bid = (int)blockIdx.x;          // 0..511
    const int xcd = bid & 7;
    const int lid = bid >> 3;                 // 0..63
    const int bh  = ((lid >> 3) << 3) | xcd;  // 0..63, bh%8 == xcd
    const int xq  = lid & 7;
    const int q0b = (NXQ - 1 - xq) * QBLK;    // big (long) blocks dispatch first

    const size_t base = (size_t)bh * S_DIM * D_DIM;
    const float* Qb = Q + base;
    const float* Kb = K + base;
    const float* Vb = V + base;

    // ---- staging assignment: thread -> (row skv, 8-float chunk sd8) ----
    const int skv = tid >> 4;   // 0..31
    const int sd8 = tid & 15;   // 0..15
    const float* kgp = Kb + (size_t)skv * D_DIM + sd8 * 8;
    const float* vgp = Vb + (size_t)skv * D_DIM + sd8 * 8;
    const uint32_t koff = (uint32_t)((skv * 256 + sd8 * 16) ^ ((skv & 7) << 4));
    const uint32_t voff = (uint32_t)((((sd8 >> 1) * 2 + ((skv >> 2) & 1)) * 256
                            + (sd8 & 1) * 8 + (skv & 3) * 16 + (skv >> 3) * 64) * 2);

    auto stage_load = [&](StageRegs& R, int t) {
        const size_t off = (size_t)t * KVBLK * D_DIM;
        R.k0 = *reinterpret_cast<const float4*>(kgp + off);
        R.k1 = *reinterpret_cast<const float4*>(kgp + off + 4);
        R.v0 = *reinterpret_cast<const float4*>(vgp + off);
        R.v1 = *reinterpret_cast<const float4*>(vgp + off + 4);
    };
    auto stage_write = [&](const StageRegs& R, int buf) {
        bf16x8 kb, vb8;
        kb[0] = (__bf16)R.k0.x; kb[1] = (__bf16)R.k0.y; kb[2] = (__bf16)R.k0.z; kb[3] = (__bf16)R.k0.w;
        kb[4] = (__bf16)R.k1.x; kb[5] = (__bf16)R.k1.y; kb[6] = (__bf16)R.k1.z; kb[7] = (__bf16)R.k1.w;
        vb8[0] = (__bf16)R.v0.x; vb8[1] = (__bf16)R.v0.y; vb8[2] = (__bf16)R.v0.z; vb8[3] = (__bf16)R.v0.w;
        vb8[4] = (__bf16)R.v1.x; vb8[5] = (__bf16)R.v1.y; vb8[6] = (__bf16)R.v1.z; vb8[7] = (__bf16)R.v1.w;
        *reinterpret_cast<bf16x8*>((char*)&k_lds[buf][0] + koff) = kb;
        *reinterpret_cast<bf16x8*>((char*)&v_lds[buf][0] + voff) = vb8;
    };

    // ---- Q fragments, 2 row-halves per wave (scale folded) ----
    const float qs = 0.08838834764831845f;
    bf16x8 aq[2][4];
    #pragma unroll
    for (int u = 0; u < 2; ++u)
        #pragma unroll
        for (int ch = 0; ch < 4; ++ch)
            aq[u][ch] = load_cvt8_scaled(
                Qb + (size_t)(q0b + wv * 32 + u * 16 + c) * D_DIM + ch * 32 + g * 8, qs);

    f32x4 o_acc[2][8];
    #pragma unroll
    for (int u = 0; u < 2; ++u)
        #pragma unroll
        for (int i = 0; i < 8; ++i) o_acc[u][i] = f32x4{0.f, 0.f, 0.f, 0.f};
    float m_run[2][4], l_run[2][4];
    #pragma unroll
    for (int u = 0; u < 2; ++u)
        #pragma unroll
        for (int r = 0; r < 4; ++r) { m_run[u][r] = -3.0e38f; l_run[u][r] = 0.f; }

    const int nt = q0b / KVBLK + QBLK / KVBLK;   // >= 8

    auto compute_tile = [&](int t, int buf) {
        const int kvb = t * KVBLK;
        const char* kbp = (const char*)&k_lds[buf][0];

        // V tr-reads issued once, shared by both row-halves
        const uint32_t vbase = lds_off(&v_lds[buf][0]) + (uint32_t)lane * 8u;
        u32x2 tr[16];
        #pragma unroll
        for (int d0 = 0; d0 < 8; ++d0) {
            const uint32_t a0 = vbase + d0 * 1024;
            asm volatile("ds_read_b64_tr_b16 %0, %1" : "=v"(tr[2 * d0]) : "v"(a0));
            asm volatile("ds_read_b64_tr_b16 %0, %1 offset:512" : "=v"(tr[2 * d0 + 1]) : "v"(a0));
        }

        #pragma unroll
        for (int u = 0; u < 2; ++u) {
            const int q0w = q0b + wv * 32 + u * 16;

            // ---- QK^T ----
            f32x4 s[2];
            __builtin_amdgcn_s_setprio(1);
            #pragma unroll
            for (int n = 0; n < 2; ++n) {
                f32x4 acc = f32x4{0.f, 0.f, 0.f, 0.f};
                #pragma unroll
                for (int ch = 0; ch < 4; ++ch) {
                    const uint32_t off =
                        (uint32_t)(((n * 16 + c) * 256 + ch * 64 + g * 16) ^ ((c & 7) << 4));
                    bf16x8 bk = *reinterpret_cast<const bf16x8*>(kbp + off);
                    acc = __builtin_amdgcn_mfma_f32_16x16x32_bf16(aq[u][ch], bk, acc, 0, 0, 0);
                }
                s[n] = acc;
            }
            __builtin_amdgcn_s_setprio(0);

            // ---- causal mask ----
            if (kvb + KVBLK - 1 > q0w) {
                #pragma unroll
                for (int n = 0; n < 2; ++n) {
                    const int kvc = kvb + n * 16 + c;
                    #pragma unroll
                    for (int r = 0; r < 4; ++r) {
                        if (kvc > q0w + g * 4 + r) s[n][r] = -1.0e30f;
                    }
                }
            }

            // ---- online softmax ----
            float sf[4];
            #pragma unroll
            for (int r = 0; r < 4; ++r) {
                float tm = fmaxf(s[0][r], s[1][r]);
                tm = fmaxf(tm, __shfl_xor(tm, 1));
                tm = fmaxf(tm, __shfl_xor(tm, 2));
                tm = fmaxf(tm, __shfl_xor(tm, 4));
                tm = fmaxf(tm, __shfl_xor(tm, 8));
                const float mn = fmaxf(m_run[u][r], tm);
                sf[r] = __expf(m_run[u][r] - mn);
                m_run[u][r] = mn;
                const float p0 = __expf(s[0][r] - mn);
                const float p1 = __expf(s[1][r] - mn);
                s[0][r] = p0; s[1][r] = p1;
                float rs = p0 + p1;
                rs += __shfl_xor(rs, 1);
                rs += __shfl_xor(rs, 2);
                rs += __shfl_xor(rs, 4);
                rs += __shfl_xor(rs, 8);
                l_run[u][r] = l_run[u][r] * sf[r] + rs;
            }
            #pragma unroll
            for (int d0 = 0; d0 < 8; ++d0)
                #pragma unroll
                for (int r = 0; r < 4; ++r) o_acc[u][d0][r] *= sf[r];

            // ---- P -> LDS (D-layout) -> A-fragment ----
            #pragma unroll
            for (int n = 0; n < 2; ++n)
                #pragma unroll
                for (int r = 0; r < 4; ++r)
                    p_lds[wv][u][g * 4 + r][n * 16 + c] = (__bf16)s[n][r];
            const bf16x8 pa = *reinterpret_cast<const bf16x8*>(&p_lds[wv][u][c][g * 8]);

            // tr results + P must be resident before the MFMAs (rule #18 fence)
            asm volatile("s_waitcnt lgkmcnt(0)");
            __builtin_amdgcn_sched_barrier(0);

            // ---- PV ----
            __builtin_amdgcn_s_setprio(1);
            #pragma unroll
            for (int d0 = 0; d0 < 8; ++d0) {
                u32x4 bu;
                bu[0] = tr[2 * d0][0]; bu[1] = tr[2 * d0][1];
                bu[2] = tr[2 * d0 + 1][0]; bu[3] = tr[2 * d0 + 1][1];
                bf16x8 bv = __builtin_bit_cast(bf16x8, bu);
                o_acc[u][d0] = __builtin_amdgcn_mfma_f32_16x16x32_bf16(pa, bv, o_acc[u][d0], 0, 0, 0);
            }
            __builtin_amdgcn_s_setprio(0);
        }
    };

    // ---- prologue: tile 0 staged, tile 1 in flight ----
    StageRegs A, B;
    stage_load(A, 0);
    stage_write(A, 0);
    stage_load(B, 1);

    int t = 0;
    for (;;) {
        __syncthreads();
        compute_tile(t, 0);
        if (t + 1 >= nt) break;
        if (t + 2 < nt) stage_load(A, t + 2);   // issued before B's write: counted vmcnt
        stage_write(B, 1);
        __syncthreads();
        compute_tile(t + 1, 1);
        if (t + 2 >= nt) break;
        if (t + 3 < nt) stage_load(B, t + 3);
        stage_write(A, 0);
        t += 2;
    }

    // ---- epilogue ----
    #pragma unroll
    for (int u = 0; u < 2; ++u)
        #pragma unroll
        for (int r = 0; r < 4; ++r) {
            const float inv = 1.0f / l_run[u][r];
            float* op = O + base + (size_t)(q0b + wv * 32 + u * 16 + g * 4 + r) * D_DIM + c;
            #pragma unroll
            for (int d0 = 0; d0 < 8; ++d0) op[d0 * 16] = o_acc[u][d0][r] * inv;
        }
}

extern "C" void kernel_launch(void* const* d_in, const int* in_sizes, int n_in,
                              void* d_out, int out_size, void* d_ws, size_t ws_size,
                              hipStream_t stream) {
    const float* Q = (const float*)d_in[0];
    const float* K = (const float*)d_in[1];
    const float* V = (const float*)d_in[2];
    float* O = (float*)d_out;
    const int bh = in_sizes[0] / (S_DIM * D_DIM);   // B*H = 64
    dim3 grid(NXQ * bh);
    attn_fwd<<<grid, 512, 0, stream>>>(Q, K, V, O);
}

// Round 5
// 372.204 us; speedup vs baseline: 1.7016x; 1.7016x over previous
//
#include <hip/hip_runtime.h>
#include <hip/hip_bf16.h>
#include <stdint.h>

#define S_DIM 2048
#define D_DIM 128
#define QBLK 256          // 8 waves x 32 q-rows
#define KVBLK 64
#define NW 8

typedef __attribute__((ext_vector_type(8)))  __bf16 bf16x8;
typedef __attribute__((ext_vector_type(16))) float  f32x16;
typedef __attribute__((ext_vector_type(2)))  unsigned int u32x2;
typedef __attribute__((ext_vector_type(4)))  unsigned int u32x4;

__device__ __forceinline__ uint32_t lds_off(const void* p) {
    return (uint32_t)(uintptr_t)p;       // low 32 bits of LDS flat addr = byte offset
}
__device__ __forceinline__ uint32_t pk2(float lo, float hi) {
    unsigned short a = __builtin_bit_cast(unsigned short, (__bf16)lo);
    unsigned short b = __builtin_bit_cast(unsigned short, (__bf16)hi);
    return (uint32_t)a | ((uint32_t)b << 16);
}

struct StageRegs { float4 k0, k1, k2, k3, v0, v1, v2, v3; };

// V window layout: element idx = 72*W + (d&15) + 16*(kv&3)   [72 elems = 144 B stride]
//   W = 2*(d>>5) + ((d>>4)&1) + 8*((kv>>2)&1) + 16*((kv>>3)&1) + 32*(kv>>4)
// tr-read offsets: jhi(+1152B), ks(+4608B), nblk(+288B), ch(+144B), hi(+2304B)
#define TRSET(p0,p1,p2,p3,p4,p5,p6,p7, A) \
  asm volatile("ds_read_b64_tr_b16 %0, %1"              : "=v"(p0) : "v"(A)); \
  asm volatile("ds_read_b64_tr_b16 %0, %1 offset:1152"  : "=v"(p1) : "v"(A)); \
  asm volatile("ds_read_b64_tr_b16 %0, %1 offset:4608"  : "=v"(p2) : "v"(A)); \
  asm volatile("ds_read_b64_tr_b16 %0, %1 offset:5760"  : "=v"(p3) : "v"(A)); \
  asm volatile("ds_read_b64_tr_b16 %0, %1 offset:9216"  : "=v"(p4) : "v"(A)); \
  asm volatile("ds_read_b64_tr_b16 %0, %1 offset:10368" : "=v"(p5) : "v"(A)); \
  asm volatile("ds_read_b64_tr_b16 %0, %1 offset:13824" : "=v"(p6) : "v"(A)); \
  asm volatile("ds_read_b64_tr_b16 %0, %1 offset:14976" : "=v"(p7) : "v"(A));

#define MFMA4(nb, q0,q1,q2,q3,q4,q5,q6,q7)                                          \
  { u32x4 bu0 = {q0[0], q0[1], q1[0], q1[1]};                                       \
    o[nb] = __builtin_amdgcn_mfma_f32_32x32x16_bf16(                                \
        __builtin_bit_cast(bf16x8, pa0), __builtin_bit_cast(bf16x8, bu0), o[nb],0,0,0); \
    u32x4 bu1 = {q2[0], q2[1], q3[0], q3[1]};                                       \
    o[nb] = __builtin_amdgcn_mfma_f32_32x32x16_bf16(                                \
        __builtin_bit_cast(bf16x8, pa1), __builtin_bit_cast(bf16x8, bu1), o[nb],0,0,0); \
    u32x4 bu2 = {q4[0], q4[1], q5[0], q5[1]};                                       \
    o[nb] = __builtin_amdgcn_mfma_f32_32x32x16_bf16(                                \
        __builtin_bit_cast(bf16x8, pa2), __builtin_bit_cast(bf16x8, bu2), o[nb],0,0,0); \
    u32x4 bu3 = {q6[0], q6[1], q7[0], q7[1]};                                       \
    o[nb] = __builtin_amdgcn_mfma_f32_32x32x16_bf16(                                \
        __builtin_bit_cast(bf16x8, pa3), __builtin_bit_cast(bf16x8, bu3), o[nb],0,0,0); }

__global__ __launch_bounds__(512, 2)
void attn_fwd(const float* __restrict__ Q, const float* __restrict__ K,
              const float* __restrict__ V, float* __restrict__ O) {
    __shared__ __bf16 k_lds[2][KVBLK * D_DIM];           // row-major, XOR ((row&7)<<4) on col bytes
    __shared__ __align__(16) char v_lds[2][18432];       // 128 windows x 144 B

    const int tid  = threadIdx.x;
    const int lane = tid & 63;
    const int wv   = tid >> 6;
    const int hi   = lane >> 5;          // 0/1
    const int qcol = lane & 31;

    // ---- block mapping: XCD-pinned by bh, makespan-paired jb (7-p with p) ----
    const int bid  = (int)blockIdx.x;            // 0..511
    const int half = bid >> 8;
    const int idx  = bid & 255;
    const int xcd  = idx & 7;
    const int sub  = idx >> 3;                   // 0..31
    const int bhg  = sub & 7;
    const int pp   = sub >> 3;                   // 0..3
    const int jb   = half ? pp : 7 - pp;         // long blocks dispatch first
    const int bh   = bhg * 8 + xcd;              // bh % 8 == xcd
    const int q0b  = jb * QBLK;
    const int q0w  = q0b + wv * 32;
    const int qg   = q0w + qcol;                 // this lane's q row (S-layout)

    const size_t base = (size_t)bh * S_DIM * D_DIM;
    const float* Qb = Q + base;
    const float* Kb = K + base;
    const float* Vb = V + base;

    // ---- staging coords: thread -> (row skv 0..63, 16-float chunk dc 0..7) ----
    const int skv = tid >> 3;
    const int dc  = tid & 7;
    const float* kgp = Kb + (size_t)skv * D_DIM + dc * 16;
    const float* vgp = Vb + (size_t)skv * D_DIM + dc * 16;
    const uint32_t kxorw = (uint32_t)((skv & 7) << 4);
    const uint32_t koff0 = (uint32_t)(skv * 256 + ((dc * 32) ^ kxorw));
    const uint32_t koff1 = (uint32_t)(skv * 256 + ((dc * 32 + 16) ^ kxorw));
    const uint32_t voffB = (uint32_t)(144 * (dc + 8 * ((skv >> 2) & 1)
                                + 16 * ((skv >> 3) & 1) + 32 * (skv >> 4))
                                + 32 * (skv & 3));

    auto stage_load = [&](StageRegs& R, int t) {
        const size_t off = (size_t)t * KVBLK * D_DIM;
        R.k0 = *reinterpret_cast<const float4*>(kgp + off);
        R.k1 = *reinterpret_cast<const float4*>(kgp + off + 4);
        R.k2 = *reinterpret_cast<const float4*>(kgp + off + 8);
        R.k3 = *reinterpret_cast<const float4*>(kgp + off + 12);
        R.v0 = *reinterpret_cast<const float4*>(vgp + off);
        R.v1 = *reinterpret_cast<const float4*>(vgp + off + 4);
        R.v2 = *reinterpret_cast<const float4*>(vgp + off + 8);
        R.v3 = *reinterpret_cast<const float4*>(vgp + off + 12);
    };
    auto stage_write = [&](const StageRegs& R, int buf) {
        bf16x8 a, b;
        a[0]=(__bf16)R.k0.x; a[1]=(__bf16)R.k0.y; a[2]=(__bf16)R.k0.z; a[3]=(__bf16)R.k0.w;
        a[4]=(__bf16)R.k1.x; a[5]=(__bf16)R.k1.y; a[6]=(__bf16)R.k1.z; a[7]=(__bf16)R.k1.w;
        b[0]=(__bf16)R.k2.x; b[1]=(__bf16)R.k2.y; b[2]=(__bf16)R.k2.z; b[3]=(__bf16)R.k2.w;
        b[4]=(__bf16)R.k3.x; b[5]=(__bf16)R.k3.y; b[6]=(__bf16)R.k3.z; b[7]=(__bf16)R.k3.w;
        char* kp = (char*)&k_lds[buf][0];
        *reinterpret_cast<bf16x8*>(kp + koff0) = a;
        *reinterpret_cast<bf16x8*>(kp + koff1) = b;
        bf16x8 c, d;
        c[0]=(__bf16)R.v0.x; c[1]=(__bf16)R.v0.y; c[2]=(__bf16)R.v0.z; c[3]=(__bf16)R.v0.w;
        c[4]=(__bf16)R.v1.x; c[5]=(__bf16)R.v1.y; c[6]=(__bf16)R.v1.z; c[7]=(__bf16)R.v1.w;
        d[0]=(__bf16)R.v2.x; d[1]=(__bf16)R.v2.y; d[2]=(__bf16)R.v2.z; d[3]=(__bf16)R.v2.w;
        d[4]=(__bf16)R.v3.x; d[5]=(__bf16)R.v3.y; d[6]=(__bf16)R.v3.z; d[7]=(__bf16)R.v3.w;
        char* vp = (char*)&v_lds[buf][0] + voffB;
        *reinterpret_cast<bf16x8*>(vp) = c;
        *reinterpret_cast<bf16x8*>(vp + 16) = d;
    };

    // ---- Q B-fragments: lane holds Q[qg][ch*16 + hi*8 + j], scale folded ----
    const float qs = 0.08838834764831845f;
    bf16x8 aq[8];
    #pragma unroll
    for (int ch = 0; ch < 8; ++ch) {
        const float* qp = Qb + (size_t)qg * D_DIM + ch * 16 + hi * 8;
        float4 x = *reinterpret_cast<const float4*>(qp);
        float4 y = *reinterpret_cast<const float4*>(qp + 4);
        bf16x8 r;
        r[0]=(__bf16)(x.x*qs); r[1]=(__bf16)(x.y*qs); r[2]=(__bf16)(x.z*qs); r[3]=(__bf16)(x.w*qs);
        r[4]=(__bf16)(y.x*qs); r[5]=(__bf16)(y.y*qs); r[6]=(__bf16)(y.z*qs); r[7]=(__bf16)(y.w*qs);
        aq[ch] = r;
    }

    bf16x8 vones;
    #pragma unroll
    for (int j = 0; j < 8; ++j) vones[j] = (__bf16)1.0f;

    f32x16 o[4], l_acc;
    #pragma unroll
    for (int i = 0; i < 16; ++i) { o[0][i]=0.f; o[1][i]=0.f; o[2][i]=0.f; o[3][i]=0.f; l_acc[i]=0.f; }
    float m_run = -3.0e38f;

    const int nt = 4 * (jb + 1);   // always even

    auto compute_tile = [&](int t, int buf) {
        const int kvb = t * KVBLK;
        if (kvb > q0w + 31) return;            // fully-masked for this wave

        // ---- QK^T (swapped): S^T[kv][q], A = K frag, B = Q frag ----
        const char* kbp = (const char*)&k_lds[buf][0];
        const uint32_t kxor = (uint32_t)((qcol & 7) << 4);
        f32x16 s0, s1;
        #pragma unroll
        for (int i = 0; i < 16; ++i) { s0[i] = 0.f; s1[i] = 0.f; }
        #pragma unroll
        for (int ch = 0; ch < 8; ++ch) {
            const uint32_t off = (uint32_t)(qcol * 256 + ((ch * 32 + hi * 16) ^ kxor));
            bf16x8 k0 = *reinterpret_cast<const bf16x8*>(kbp + off);
            bf16x8 k1 = *reinterpret_cast<const bf16x8*>(kbp + off + 8192);
            s0 = __builtin_amdgcn_mfma_f32_32x32x16_bf16(k0, aq[ch], s0, 0, 0, 0);
            s1 = __builtin_amdgcn_mfma_f32_32x32x16_bf16(k1, aq[ch], s1, 0, 0, 0);
        }

        // ---- causal mask ----
        if (kvb + KVBLK - 1 > q0w) {
            #pragma unroll
            for (int r = 0; r < 16; ++r) {
                const int kv0 = kvb + (r & 3) + 8 * (r >> 2) + 4 * hi;
                if (kv0 > qg)      s0[r] = -1.0e30f;
                if (kv0 + 32 > qg) s1[r] = -1.0e30f;
            }
        }

        // ---- row max (in-lane 31 ops + 1 cross) ----
        float pm = s0[0];
        #pragma unroll
        for (int r = 1; r < 16; ++r) pm = fmaxf(pm, s0[r]);
        #pragma unroll
        for (int r = 0; r < 16; ++r) pm = fmaxf(pm, s1[r]);
        pm = fmaxf(pm, __shfl_xor(pm, 32));

        // ---- defer-max: rescale only when needed (cold path) ----
        if (__any(pm - m_run > 8.0f)) {
            const float mn = fmaxf(m_run, pm);
            const float sc = __expf(m_run - mn);
            m_run = mn;
            #pragma unroll
            for (int r = 0; r < 16; ++r) {
                const float scr = __shfl(sc, (r & 3) + 8 * (r >> 2) + 4 * hi);
                o[0][r] *= scr; o[1][r] *= scr; o[2][r] *= scr; o[3][r] *= scr;
                l_acc[r] *= scr;
            }
        }

        // ---- P = exp(S - m)  (bounded by e^8) ----
        #pragma unroll
        for (int r = 0; r < 16; ++r) s0[r] = __expf(s0[r] - m_run);
        #pragma unroll
        for (int r = 0; r < 16; ++r) s1[r] = __expf(s1[r] - m_run);

        // ---- V tr-reads for nblk 0,1 issued early ----
        const uint32_t vb_lane = lds_off(&v_lds[buf][0]) + (uint32_t)((lane & 15) * 8)
                               + (uint32_t)(((lane >> 4) & 1) * 144) + (uint32_t)(hi * 2304);
        u32x2 a0,a1,a2,a3,a4,a5,a6,a7, b0,b1,b2,b3,b4,b5,b6,b7;
        TRSET(a0,a1,a2,a3,a4,a5,a6,a7, vb_lane);
        const uint32_t vb1 = vb_lane + 288;
        TRSET(b0,b1,b2,b3,b4,b5,b6,b7, vb1);

        // ---- pack P -> bf16 A-fragments via permlane32_swap ----
        uint32_t w00 = pk2(s0[0],  s0[1]),  w01 = pk2(s0[2],  s0[3]);
        uint32_t w02 = pk2(s0[4],  s0[5]),  w03 = pk2(s0[6],  s0[7]);
        asm("v_permlane32_swap_b32 %0, %1" : "+v"(w00), "+v"(w02));
        asm("v_permlane32_swap_b32 %0, %1" : "+v"(w01), "+v"(w03));
        u32x4 pa0 = {w00, w01, w02, w03};
        uint32_t w10 = pk2(s0[8],  s0[9]),  w11 = pk2(s0[10], s0[11]);
        uint32_t w12 = pk2(s0[12], s0[13]), w13 = pk2(s0[14], s0[15]);
        asm("v_permlane32_swap_b32 %0, %1" : "+v"(w10), "+v"(w12));
        asm("v_permlane32_swap_b32 %0, %1" : "+v"(w11), "+v"(w13));
        u32x4 pa1 = {w10, w11, w12, w13};
        uint32_t w20 = pk2(s1[0],  s1[1]),  w21 = pk2(s1[2],  s1[3]);
        uint32_t w22 = pk2(s1[4],  s1[5]),  w23 = pk2(s1[6],  s1[7]);
        asm("v_permlane32_swap_b32 %0, %1" : "+v"(w20), "+v"(w22));
        asm("v_permlane32_swap_b32 %0, %1" : "+v"(w21), "+v"(w23));
        u32x4 pa2 = {w20, w21, w22, w23};
        uint32_t w30 = pk2(s1[8],  s1[9]),  w31 = pk2(s1[10], s1[11]);
        uint32_t w32 = pk2(s1[12], s1[13]), w33 = pk2(s1[14], s1[15]);
        asm("v_permlane32_swap_b32 %0, %1" : "+v"(w30), "+v"(w32));
        asm("v_permlane32_swap_b32 %0, %1" : "+v"(w31), "+v"(w33));
        u32x4 pa3 = {w30, w31, w32, w33};

        // ---- l += P . ones  (lands in O layout -> no redistribution ever) ----
        l_acc = __builtin_amdgcn_mfma_f32_32x32x16_bf16(__builtin_bit_cast(bf16x8, pa0), vones, l_acc, 0,0,0);
        l_acc = __builtin_amdgcn_mfma_f32_32x32x16_bf16(__builtin_bit_cast(bf16x8, pa1), vones, l_acc, 0,0,0);
        l_acc = __builtin_amdgcn_mfma_f32_32x32x16_bf16(__builtin_bit_cast(bf16x8, pa2), vones, l_acc, 0,0,0);
        l_acc = __builtin_amdgcn_mfma_f32_32x32x16_bf16(__builtin_bit_cast(bf16x8, pa3), vones, l_acc, 0,0,0);

        // ---- PV, ping-pong tr-read sets, counted lgkmcnt ----
        asm volatile("s_waitcnt lgkmcnt(8)");
        __builtin_amdgcn_sched_barrier(0);
        __builtin_amdgcn_s_setprio(1);
        MFMA4(0, a0,a1,a2,a3,a4,a5,a6,a7);
        __builtin_amdgcn_s_setprio(0);
        const uint32_t vb2 = vb_lane + 576;
        TRSET(a0,a1,a2,a3,a4,a5,a6,a7, vb2);
        asm volatile("s_waitcnt lgkmcnt(8)");
        __builtin_amdgcn_sched_barrier(0);
        __builtin_amdgcn_s_setprio(1);
        MFMA4(1, b0,b1,b2,b3,b4,b5,b6,b7);
        __builtin_amdgcn_s_setprio(0);
        const uint32_t vb3 = vb_lane + 864;
        TRSET(b0,b1,b2,b3,b4,b5,b6,b7, vb3);
        asm volatile("s_waitcnt lgkmcnt(8)");
        __builtin_amdgcn_sched_barrier(0);
        __builtin_amdgcn_s_setprio(1);
        MFMA4(2, a0,a1,a2,a3,a4,a5,a6,a7);
        __builtin_amdgcn_s_setprio(0);
        asm volatile("s_waitcnt lgkmcnt(0)");
        __builtin_amdgcn_sched_barrier(0);
        __builtin_amdgcn_s_setprio(1);
        MFMA4(3, b0,b1,b2,b3,b4,b5,b6,b7);
        __builtin_amdgcn_s_setprio(0);
    };

    // ---- pipeline: depth-2 register staging, 1 barrier per tile ----
    StageRegs SA, SB;
    stage_load(SA, 0);
    stage_write(SA, 0);
    stage_load(SB, 1);

    for (int t = 0; ; t += 2) {
        __syncthreads();
        stage_write(SB, 1);                       // tile t+1 -> buf1
        if (t + 2 < nt) stage_load(SA, t + 2);
        compute_tile(t, 0);
        __syncthreads();
        if (t + 2 < nt) stage_write(SA, 0);       // tile t+2 -> buf0
        if (t + 3 < nt) stage_load(SB, t + 3);
        compute_tile(t + 1, 1);
        if (t + 4 > nt) break;
    }

    // ---- epilogue: O = o / l (same layout, no redistribution) ----
    #pragma unroll
    for (int r = 0; r < 16; ++r) {
        const float iv = 1.0f / l_acc[r];
        float* op = O + base
                  + (size_t)(q0b + wv * 32 + (r & 3) + 8 * (r >> 2) + 4 * hi) * D_DIM + qcol;
        op[0]  = o[0][r] * iv;
        op[32] = o[1][r] * iv;
        op[64] = o[2][r] * iv;
        op[96] = o[3][r] * iv;
    }
}

extern "C" void kernel_launch(void* const* d_in, const int* in_sizes, int n_in,
                              void* d_out, int out_size, void* d_ws, size_t ws_size,
                              hipStream_t stream) {
    const float* Q = (const float*)d_in[0];
    const float* K = (const float*)d_in[1];
    const float* V = (const float*)d_in[2];
    float* O = (float*)d_out;
    const int bh = in_sizes[0] / (S_DIM * D_DIM);   // B*H = 64
    dim3 grid(bh * (S_DIM / QBLK));                 // 512 blocks
    attn_fwd<<<grid, 512, 0, stream>>>(Q, K, V, O);
}